// Round 2
// baseline (54.642 us; speedup 1.0000x reference)
//
#include <hip/hip_runtime.h>
#include <hip/hip_bf16.h>
#include <math.h>

// Problem constants (fixed by the reference):
//   D=5 directions, E=16 experts, B=64 batch, P=4096 patches/expert, W=3 window
//   Q,K,V: [D,E,B,P] f32; betas: [E,E] f32; temperature: [1] f32; routes: [E,W] int
//   out: [B, E*P] f32, out[b, e*P+p] = mean_d softmax_w(Q*c)_w . Vnbr_w

#define D_ 5
#define E_ 16
#define B_ 64
#define P_ 4096
#define W_ 3
#define ROWS (D_*E_*B_)   // 5120 (d,e,b) rows

// ---------------- Phase 1: Ksum / Vmean row reductions ----------------
// wave-per-row: 4 waves/block, one (d,e,b) row each. No LDS, no barriers.
// Each lane: 16 K float4 + 16 V float4 (issued 8+8 at a time, 16 in flight).
__global__ __launch_bounds__(256) void cga_phase1(
    const float* __restrict__ K, const float* __restrict__ V,
    float* __restrict__ ksum, float* __restrict__ vmean)
{
    const int wid  = threadIdx.x >> 6;
    const int lane = threadIdx.x & 63;
    const int row  = (blockIdx.x << 2) | wid;     // [0, 5120)
    const float4* k4 = (const float4*)(K + (size_t)row * P_);
    const float4* v4 = (const float4*)(V + (size_t)row * P_);

    float ks = 0.f, vs = 0.f;
    #pragma unroll
    for (int h = 0; h < 2; ++h) {
        float4 a[8], c[8];
        #pragma unroll
        for (int i = 0; i < 8; ++i) a[i] = k4[lane + (h * 8 + i) * 64];
        #pragma unroll
        for (int i = 0; i < 8; ++i) c[i] = v4[lane + (h * 8 + i) * 64];
        #pragma unroll
        for (int i = 0; i < 8; ++i) {
            ks += (a[i].x + a[i].y) + (a[i].z + a[i].w);
            vs += (c[i].x + c[i].y) + (c[i].z + c[i].w);
        }
    }
    // wave64 butterfly reduce (no LDS)
    #pragma unroll
    for (int off = 1; off < 64; off <<= 1) {
        ks += __shfl_xor(ks, off);
        vs += __shfl_xor(vs, off);
    }
    if (lane == 0) {
        ksum[row]  = ks;
        vmean[row] = vs * (1.0f / (float)P_);
    }
}

// ---------------- Phase 2: stream Q, 3-way softmax, mean over d ----------------
__device__ __forceinline__ float attend1(float q, const float c[3], const float v[3])
{
    float s0 = q * c[0], s1 = q * c[1], s2 = q * c[2];
    float m  = fmaxf(fmaxf(s0, s1), s2);
    float e0 = __expf(s0 - m), e1 = __expf(s1 - m), e2 = __expf(s2 - m);
    float num = e0 * v[0] + e1 * v[1] + e2 * v[2];
    float den = e0 + e1 + e2;
    return __fdividef(num, den);
}

// grid = E*B*(P/2048) = 2048 blocks; 256 threads; 8 floats/thread/direction-set
__global__ __launch_bounds__(256) void cga_phase2(
    const float* __restrict__ Q,
    const float* __restrict__ ksum, const float* __restrict__ vmean,
    const float* __restrict__ betas, const float* __restrict__ temp,
    const int* __restrict__ routes,
    float* __restrict__ out)
{
    const int blk   = blockIdx.x;
    const int chunk = blk & 1;        // 2 chunks of 2048 patches per (e,b)
    const int eb    = blk >> 1;
    const int b     = eb & (B_ - 1);
    const int e     = eb >> 6;
    const int t     = threadIdx.x;
    const int p0    = chunk * 2048 + t * 4;

    // Issue ALL Q loads first — the coefficient gather below overlaps their latency.
    float4 qa[D_], qb[D_];
    #pragma unroll
    for (int d = 0; d < D_; ++d) {
        const float* qp = Q + ((size_t)((d * E_ + e) * B_ + b)) * P_;
        qa[d] = *(const float4*)(qp + p0);
        qb[d] = *(const float4*)(qp + p0 + 1024);
    }

    __shared__ float sc[D_][W_];      // score coeffs  c[d][w] = Ksum*scale*beta
    __shared__ float sv[D_][W_];      // value coeffs  v[d][w] = Vmean
    if (t < D_ * W_) {
        const int d = t / W_;
        const int w = t - d * W_;
        const int rw = routes[e * W_ + w];
        const float scale = 1.0f / (11.313708498984760f * fabsf(temp[0])); // sqrt(128)
        float bw = 1.0f;
        if (rw != e) bw = 1.0f / (1.0f + __expf(-betas[e * E_ + rw]));
        const int idx = (d * E_ + rw) * B_ + b;
        sc[d][w] = ksum[idx] * scale * bw;
        sv[d][w] = vmean[idx];
    }
    __syncthreads();

    float4 acc0 = make_float4(0.f, 0.f, 0.f, 0.f);
    float4 acc1 = make_float4(0.f, 0.f, 0.f, 0.f);
    #pragma unroll
    for (int d = 0; d < D_; ++d) {
        float rc[W_], rv[W_];
        #pragma unroll
        for (int w = 0; w < W_; ++w) { rc[w] = sc[d][w]; rv[w] = sv[d][w]; }
        acc0.x += attend1(qa[d].x, rc, rv);
        acc0.y += attend1(qa[d].y, rc, rv);
        acc0.z += attend1(qa[d].z, rc, rv);
        acc0.w += attend1(qa[d].w, rc, rv);
        acc1.x += attend1(qb[d].x, rc, rv);
        acc1.y += attend1(qb[d].y, rc, rv);
        acc1.z += attend1(qb[d].z, rc, rv);
        acc1.w += attend1(qb[d].w, rc, rv);
    }
    const float inv_d = 1.0f / (float)D_;
    acc0.x *= inv_d; acc0.y *= inv_d; acc0.z *= inv_d; acc0.w *= inv_d;
    acc1.x *= inv_d; acc1.y *= inv_d; acc1.z *= inv_d; acc1.w *= inv_d;

    float* ob = out + (size_t)b * (E_ * P_) + (size_t)e * P_ + p0;
    *(float4*)ob          = acc0;
    *(float4*)(ob + 1024) = acc1;
}

extern "C" void kernel_launch(void* const* d_in, const int* in_sizes, int n_in,
                              void* d_out, int out_size, void* d_ws, size_t ws_size,
                              hipStream_t stream) {
    const float* Q     = (const float*)d_in[0];
    const float* K     = (const float*)d_in[1];
    const float* V     = (const float*)d_in[2];
    const float* betas = (const float*)d_in[3];
    const float* temp  = (const float*)d_in[4];
    const int*   routes= (const int*)d_in[5];
    float* out = (float*)d_out;

    float* ksum  = (float*)d_ws;          // ROWS floats
    float* vmean = ksum + ROWS;           // ROWS floats  (40 KB total)

    cga_phase1<<<ROWS / 4, 256, 0, stream>>>(K, V, ksum, vmean);
    cga_phase2<<<E_ * B_ * (P_ / 2048), 256, 0, stream>>>(
        Q, ksum, vmean, betas, temp, routes, out);
}